// Round 2
// baseline (191.958 us; speedup 1.0000x reference)
//
#include <hip/hip_runtime.h>

// Wide tower fused kernel, 4 threads per row for latency hiding.
//   out[b] = dot(dense[b,:13], dense_w)
//          + sum_i emb_table[i, idx[b,i]]
//          + cross0[idx[b,0]*5000+idx[b,1]] + cross1[idx[b,2]*5000+idx[b,3]]
//
// Latency-bound gather kernel: 1 thread/row gave only 1 wave/SIMD (256
// blocks on 256 CUs). 4 threads/row -> 1024 blocks -> 4 waves/SIMD, and
// each thread's serial chain of independent loads is 4x shorter.

constexpr int N_DENSE  = 13;
constexpr int N_SPARSE = 26;
constexpr int VOCAB    = 5000;
constexpr int SPLIT    = 4;   // threads cooperating on one row

__global__ __launch_bounds__(256) void wide_fused_kernel(
    const float* __restrict__ dense,       // [B, 13]
    const float* __restrict__ emb_table,   // [26, 5000]
    const float* __restrict__ cross0,      // [25e6]
    const float* __restrict__ cross1,      // [25e6]
    const float* __restrict__ dense_w,     // [13]
    const int*   __restrict__ sparse_idx,  // [B, 26] (int32)
    float*       __restrict__ out,         // [B]
    int B)
{
    int tid = blockIdx.x * blockDim.x + threadIdx.x;
    int b = tid >> 2;           // row
    int s = tid & (SPLIT - 1);  // slot within row group
    if (b >= B) return;

    const int* ir = sparse_idx + (size_t)b * N_SPARSE;

    float acc = 0.f;

    // Long-latency cross gathers first: lane 0 -> cross0, lane 1 -> cross1.
    if (s < 2) {
        int va = ir[2 * s];
        int vb = ir[2 * s + 1];
        const float* ct = (s == 0) ? cross0 : cross1;
        acc += ct[va * VOCAB + vb];   // < 2^31, int32 math safe
    }

    // Embedding gathers: positions s, s+4, ..., (<26). Idx reads are
    // coalesced across the wave (contiguous int32 region per 16 rows).
    #pragma unroll
    for (int k = 0; k < 7; ++k) {
        int i = s + SPLIT * k;
        if (i < N_SPARSE) acc += emb_table[i * VOCAB + ir[i]];
    }

    // Dense dot: j = s, s+4, s+8, s+12 (guard <13). dense_w is uniform.
    const float* dr = dense + (size_t)b * N_DENSE;
    #pragma unroll
    for (int k = 0; k < 4; ++k) {
        int j = s + SPLIT * k;
        if (j < N_DENSE) acc += dr[j] * dense_w[j];
    }

    // Reduce the 4-lane group.
    acc += __shfl_xor(acc, 1, SPLIT);
    acc += __shfl_xor(acc, 2, SPLIT);
    if (s == 0) out[b] = acc;
}

extern "C" void kernel_launch(void* const* d_in, const int* in_sizes, int n_in,
                              void* d_out, int out_size, void* d_ws, size_t ws_size,
                              hipStream_t stream) {
    const float* dense   = (const float*)d_in[0];
    const float* emb     = (const float*)d_in[1];
    const float* cross0  = (const float*)d_in[2];
    const float* cross1  = (const float*)d_in[3];
    const float* dense_w = (const float*)d_in[4];
    const int*   idx     = (const int*)d_in[5];
    float* out = (float*)d_out;

    int B = out_size;                       // [B,1] output
    const int block = 256;
    const int total = B * SPLIT;
    const int grid  = (total + block - 1) / block;
    wide_fused_kernel<<<grid, block, 0, stream>>>(
        dense, emb, cross0, cross1, dense_w, idx, out, B);
}